// Round 15
// baseline (129.507 us; speedup 1.0000x reference)
//
#include <hip/hip_runtime.h>
#include <math.h>

#define BB 128
#define OUTROW 1259   // 2+1+256+1000

typedef float vf4 __attribute__((ext_vector_type(4)));

// ---------------- bf16 helpers ----------------
__device__ __forceinline__ ushort f2b(float x) {
    unsigned u = __float_as_uint(x);
    unsigned r = (u + 0x7FFFu + ((u >> 16) & 1u)) >> 16;   // RNE
    return (ushort)r;
}
__device__ __forceinline__ uint pack2(float lo, float hi) {
    return (uint)f2b(lo) | ((uint)f2b(hi) << 16);
}
__device__ __forceinline__ float dot2bf(uint a, uint b, float c) {
    float d;
    asm("v_dot2_f32_bf16 %0, %1, %2, %3" : "=v"(d) : "v"(a), "v"(b), "v"(c));
    return d;
}

// bf16 arena (R12 layout, verified): pair-interleaved W2[kp][col] (ushort offs)
#define OFF_W0   0u        // 256 kp * 512          = 131072  (k padded 451->512)
#define OFF_RW   131072u   // 4 * 128 kp * 512      = 262144
#define OFF_CW0  393216u   // 65536
#define OFF_CRW  458752u   // 65536
#define OFF_WF   524288u   // 128 kp * 520 (260c)   = 69632
#define OFF_CW1  593920u   // 128 kp * 2048 (1024c) = 262144
#define N_TOT    856064u

// ws float-offsets
#define WS_PIX   0u
#define WS_BFA   24576u     // 428032 floats
#define WS_INP2  452608u    // 128*256 uint
#define WS_H0F   485376u
#define WS_H0P   518144u
#define WS_H1F   534528u
#define WS_H1P   567296u
#define WS_WFO   583680u    // 128*260
#define WS_NHF   616960u
#define WS_NHP   649728u
#define WS_C0F   666112u
#define WS_C0P   698880u
#define WS_C1F   715264u
#define WS_C1P   748032u
#define WS_LG    764416u    // 128*1024

__device__ __forceinline__ void dirichlet_ab(float t, float& A, float& Bv) {
    float r = t - rintf(t);
    float s256 = sinpif(256.0f * r);
    Bv = s256 * (1.0f / 256.0f);
    if (fabsf(r) < 1e-6f) {
        A = 1.0f;
    } else {
        float sp = sinpif(r), cp = cospif(r);
        A = Bv * cp / sp;
    }
}

// blocks 0..383: NUDFT interp; blocks 384+: bf16 pair-convert (R12-verified).
__global__ __launch_bounds__(256) void interp_convert_kernel(
    const float* __restrict__ image, const float* __restrict__ loc,
    const float* __restrict__ scl, float* __restrict__ pix,
    const float* __restrict__ w0, const float* __restrict__ rw,
    const float* __restrict__ wf, const float* __restrict__ cw0,
    const float* __restrict__ crw, const float* __restrict__ cw1,
    ushort* __restrict__ bfa)
{
    __shared__ float U[256 * 16];
    __shared__ float V[16 * 260];
    __shared__ float T[16 * 260];

    int bid = blockIdx.x;
    int tid = threadIdx.x;

    if (bid >= 384) {
        unsigned g = (unsigned)(bid - 384) * 256u + (unsigned)tid;
        for (unsigned j = g; j < N_TOT; j += 512u * 256u) {
            if (j < 131072u) {
                unsigned kp = j >> 9, r = j & 511u, c = r >> 1, k = 2u*kp + (r & 1u);
                bfa[OFF_W0 + j] = (k < 451u) ? f2b(w0[k * 256u + c]) : (ushort)0;
            } else if (j < 393216u) {
                unsigned jj = j - 131072u;
                unsigned kp = jj >> 9, r = jj & 511u, c = r >> 1, k = 2u*kp + (r & 1u);
                bfa[OFF_RW + jj] = f2b(rw[k * 256u + c]);
            } else if (j < 458752u) {
                unsigned jj = j - 393216u;
                unsigned kp = jj >> 9, r = jj & 511u, c = r >> 1, k = 2u*kp + (r & 1u);
                bfa[OFF_CW0 + jj] = f2b(cw0[k * 256u + c]);
            } else if (j < 524288u) {
                unsigned jj = j - 458752u;
                unsigned kp = jj >> 9, r = jj & 511u, c = r >> 1, k = 2u*kp + (r & 1u);
                bfa[OFF_CRW + jj] = f2b(crw[k * 256u + c]);
            } else if (j < 593920u) {
                unsigned jj = j - 524288u;
                unsigned kp = jj / 520u, r = jj - kp * 520u, c = r >> 1, k = 2u*kp + (r & 1u);
                bfa[OFF_WF + jj] = (c < 259u) ? f2b(wf[k * 259u + c]) : (ushort)0;
            } else {
                unsigned jj = j - 593920u;
                unsigned kp = jj / 2048u, r = jj - kp * 2048u, c = r >> 1, k = 2u*kp + (r & 1u);
                bfa[OFF_CW1 + jj] = (c < 1000u) ? f2b(cw1[k * 1000u + c]) : (ushort)0;
            }
        }
        return;
    }

    int b = bid / 3, c = bid % 3;
    float l0 = loc[2 * b], l1 = loc[2 * b + 1], sc = scl[b];

    {
        int p = tid;
        float tp = (float)p * (1.0f / 256.0f);
        #pragma unroll
        for (int iy = 0; iy < 8; ++iy) {
            float A, Bv;
            float y = ((float)iy * 0.125f - l0) * sc;
            dirichlet_ab(y - tp, A, Bv);
            int w = iy >> 1, o = iy & 1;
            U[p * 16 + w * 4 + o] = A;
            U[p * 16 + w * 4 + 2 + o] = Bv;
            float x = ((float)iy * 0.125f - l1) * sc;
            dirichlet_ab(x - tp, A, Bv);
            V[iy * 260 + p] = A;
            V[(8 + iy) * 260 + p] = Bv;
        }
    }
    __syncthreads();

    int wave = tid >> 6, lane = tid & 63;
    const float* img = image + (size_t)(b * 3 + c) * 65536 + lane * 4;

    float aA0[4] = {0, 0, 0, 0}, aA1[4] = {0, 0, 0, 0};
    float aB0[4] = {0, 0, 0, 0}, aB1[4] = {0, 0, 0, 0};
    #pragma unroll 4
    for (int p = 0; p < 256; ++p) {
        vf4 v = __builtin_nontemporal_load((const vf4*)(img + p * 256));
        const float4 u = *(const float4*)(&U[p * 16 + wave * 4]);
        aA0[0] += u.x * v[0]; aA0[1] += u.x * v[1]; aA0[2] += u.x * v[2]; aA0[3] += u.x * v[3];
        aA1[0] += u.y * v[0]; aA1[1] += u.y * v[1]; aA1[2] += u.y * v[2]; aA1[3] += u.y * v[3];
        aB0[0] += u.z * v[0]; aB0[1] += u.z * v[1]; aB0[2] += u.z * v[2]; aB0[3] += u.z * v[3];
        aB1[0] += u.w * v[0]; aB1[1] += u.w * v[1]; aB1[2] += u.w * v[2]; aB1[3] += u.w * v[3];
    }
    int iy0 = wave * 2;
    int q0 = lane * 4;
    #pragma unroll
    for (int j = 0; j < 4; ++j) {
        T[iy0 * 260 + q0 + j]       = aA0[j];
        T[(iy0 + 1) * 260 + q0 + j] = aA1[j];
        T[(8 + iy0) * 260 + q0 + j]     = aB0[j];
        T[(8 + iy0 + 1) * 260 + q0 + j] = aB1[j];
    }
    __syncthreads();

    int n = tid >> 2, sub = tid & 3;
    int iy = n >> 3, ix = n & 7;
    float s = 0.f;
    #pragma unroll 8
    for (int i = 0; i < 64; ++i) {
        int q = sub + 4 * i;
        s += T[iy * 260 + q] * V[ix * 260 + q] - T[(8 + iy) * 260 + q] * V[(8 + ix) * 260 + q];
    }
    s += __shfl_xor(s, 1);
    s += __shfl_xor(s, 2);
    if (sub == 0) pix[(b * 64 + n) * 3 + c] = s;
}

// Build packed input [128][256 kp] (k padded 451->512 with zeros).
__global__ __launch_bounds__(256) void pack_inp_kernel(
    const float* __restrict__ loc, const float* __restrict__ scl,
    const float* __restrict__ pix, const float* __restrict__ hidden,
    uint* __restrict__ inp2)
{
    int r = blockIdx.x, kp = threadIdx.x;
    int k0 = 2 * kp, k1 = k0 + 1;
    float lo = (k0 < 2) ? loc[2 * r + k0] : (k0 == 2) ? scl[r]
             : (k0 < 195) ? pix[r * 192 + (k0 - 3)]
             : (k0 < 451) ? hidden[r * 256 + (k0 - 195)] : 0.f;
    float hi = (k1 < 2) ? loc[2 * r + k1] : (k1 == 2) ? scl[r]
             : (k1 < 195) ? pix[r * 192 + (k1 - 3)]
             : (k1 < 451) ? hidden[r * 256 + (k1 - 195)] : 0.f;
    inp2[r * 256 + kp] = pack2(lo, hi);
}

// One GEMM layer: [128 rows x 16 cols per block], K = 2*KP.
// W-slice staged to LDS transposed [c][kp] with per-g +4 skew (bank spread).
// Thread (r = tid>>3, g = tid&7): 8-way kp split, 16 f32 acc, shfl reduce.
template<int KP, int MODE>   // MODE 0 none, 1 relu, 2 tanh
__global__ __launch_bounds__(1024, 1) void layer_gemm(
    const uint* __restrict__ A2, const uint* __restrict__ W2, int CW,
    int C_real, const float* __restrict__ bias, const float* __restrict__ resF,
    float* __restrict__ outF, int outLD, uint* __restrict__ out2)
{
    constexpr int KPG = KP / 8;
    constexpr int KROW = KPG + 4;          // skewed per-g row
    constexpr int KPPAD = 8 * KROW;
    __shared__ uint WL[16 * KPPAD];

    int tid = threadIdx.x;
    int col0 = blockIdx.x * 16;

    // stage W-slice: global [kp][col0+c] -> WL[c*KPPAD + g(kp)*KROW + j(kp)]
    #pragma unroll
    for (int it = 0; it < (KP * 16) / 1024; ++it) {
        int i = tid + it * 1024;
        int kp = i >> 4, c = i & 15;
        int gi = kp / KPG, ji = kp % KPG;
        WL[c * KPPAD + gi * KROW + ji] = W2[(size_t)kp * CW + col0 + c];
    }
    __syncthreads();

    int r = tid >> 3, g = tid & 7;

    uint av[KPG];
    const uint* Arow = A2 + (size_t)r * KP + g * KPG;
    #pragma unroll
    for (int j = 0; j < KPG; ++j) av[j] = Arow[j];

    float acc[16];
    #pragma unroll
    for (int c = 0; c < 16; ++c) acc[c] = 0.f;

    #pragma unroll
    for (int c = 0; c < 16; ++c) {
        const uint* wb = &WL[c * KPPAD + g * KROW];
        #pragma unroll
        for (int j4 = 0; j4 < KPG / 4; ++j4) {
            uint4 w = *(const uint4*)(wb + 4 * j4);
            acc[c] = dot2bf(w.x, av[4 * j4 + 0], acc[c]);
            acc[c] = dot2bf(w.y, av[4 * j4 + 1], acc[c]);
            acc[c] = dot2bf(w.z, av[4 * j4 + 2], acc[c]);
            acc[c] = dot2bf(w.w, av[4 * j4 + 3], acc[c]);
        }
    }

    // reduce over g (lane bits 0..2)
    #pragma unroll
    for (int c = 0; c < 16; ++c) {
        acc[c] += __shfl_xor(acc[c], 1);
        acc[c] += __shfl_xor(acc[c], 2);
        acc[c] += __shfl_xor(acc[c], 4);
    }

    // epilogue: this thread owns cols col0+2g, col0+2g+1
    int c0 = 2 * g;
    int col = col0 + c0;
    float v0 = acc[c0], v1 = acc[c0 + 1];
    if (col < C_real)     v0 += bias[col];
    if (col + 1 < C_real) v1 += bias[col + 1];
    if (resF) {
        v0 += resF[r * 256 + col];
        v1 += resF[r * 256 + col + 1];
    }
    if (MODE == 1) { v0 = fmaxf(v0, 0.f); v1 = fmaxf(v1, 0.f); }
    if (MODE == 2) { v0 = tanhf(v0);      v1 = tanhf(v1); }
    if (col < C_real)     outF[(size_t)r * outLD + col] = v0;
    if (col + 1 < C_real) outF[(size_t)r * outLD + col + 1] = v1;
    if (out2) out2[r * 128 + (col >> 1)] = pack2(v0, v1);
}

// state update: out[0..258], nh (f32 + packed)
__global__ __launch_bounds__(256) void update_kernel(
    const float* __restrict__ loc, const float* __restrict__ scl,
    const float* __restrict__ hidden, const float* __restrict__ wfo,
    float* __restrict__ nhF, uint* __restrict__ nhP, float* __restrict__ out)
{
    int r = blockIdx.x, tid = threadIdx.x;
    float* orow = out + (size_t)r * OUTROW;
    float nh = hidden[r * 256 + tid] + wfo[r * 260 + 3 + tid];
    orow[3 + tid] = nh;
    nhF[r * 256 + tid] = nh;
    float v2 = __shfl_xor(nh, 1);
    if (!(tid & 1)) nhP[r * 128 + (tid >> 1)] = pack2(nh, v2);
    if (tid < 2) orow[tid] = loc[2 * r + tid] + wfo[r * 260 + tid];
    if (tid == 2) orow[2] = scl[r] + wfo[r * 260 + 2];
}

// Per-row softmax over 1000 logits (ld 1024) -> out[259..1258].
__global__ __launch_bounds__(1024) void softmax_kernel(
    const float* __restrict__ lg, float* __restrict__ out)
{
    __shared__ float s_red[32];
    int b = blockIdx.x, tid = threadIdx.x;
    float* orow = out + (size_t)b * OUTROW;

    float lgv = (tid < 1000) ? lg[(size_t)b * 1024 + tid] : -1e30f;

    int lane = tid & 63, wid = tid >> 6;
    float m = lgv;
    #pragma unroll
    for (int off = 1; off < 64; off <<= 1) m = fmaxf(m, __shfl_xor(m, off));
    if (lane == 0) s_red[wid] = m;
    __syncthreads();
    m = s_red[0];
    #pragma unroll
    for (int w = 1; w < 16; ++w) m = fmaxf(m, s_red[w]);

    float e = (tid < 1000) ? expf(lgv - m) : 0.f;
    float lsum = e;
    #pragma unroll
    for (int off = 1; off < 64; off <<= 1) lsum += __shfl_xor(lsum, off);
    if (lane == 0) s_red[16 + wid] = lsum;
    __syncthreads();
    float total = 0.f;
    #pragma unroll
    for (int w = 0; w < 16; ++w) total += s_red[16 + w];

    if (tid < 1000) orow[259 + tid] = e / total;
}

extern "C" void kernel_launch(void* const* d_in, const int* in_sizes, int n_in,
                              void* d_out, int out_size, void* d_ws, size_t ws_size,
                              hipStream_t stream) {
    const float* image  = (const float*)d_in[0];
    const float* loc    = (const float*)d_in[1];
    const float* scl    = (const float*)d_in[2];
    const float* hidden = (const float*)d_in[3];
    const float* w0  = (const float*)d_in[4];
    const float* b0  = (const float*)d_in[5];
    const float* rw  = (const float*)d_in[6];
    const float* rb  = (const float*)d_in[7];
    const float* wf  = (const float*)d_in[8];
    const float* bf  = (const float*)d_in[9];
    const float* cw0 = (const float*)d_in[10];
    const float* cb0 = (const float*)d_in[11];
    const float* crw = (const float*)d_in[12];
    const float* crb = (const float*)d_in[13];
    const float* cw1 = (const float*)d_in[14];
    const float* cb1 = (const float*)d_in[15];

    float* ws    = (float*)d_ws;
    float* pix   = ws + WS_PIX;
    ushort* bfa  = (ushort*)(ws + WS_BFA);
    uint*  inp2  = (uint*)(ws + WS_INP2);
    float* h0f   = ws + WS_H0F;   uint* h0p = (uint*)(ws + WS_H0P);
    float* h1f   = ws + WS_H1F;   uint* h1p = (uint*)(ws + WS_H1P);
    float* wfo   = ws + WS_WFO;
    float* nhf   = ws + WS_NHF;   uint* nhp = (uint*)(ws + WS_NHP);
    float* c0f   = ws + WS_C0F;   uint* c0p = (uint*)(ws + WS_C0P);
    float* c1f   = ws + WS_C1F;   uint* c1p = (uint*)(ws + WS_C1P);
    float* lg    = ws + WS_LG;

    const uint* W0u  = (const uint*)(bfa + OFF_W0);
    const uint* RWu  = (const uint*)(bfa + OFF_RW);
    const uint* CW0u = (const uint*)(bfa + OFF_CW0);
    const uint* CRWu = (const uint*)(bfa + OFF_CRW);
    const uint* WFu  = (const uint*)(bfa + OFF_WF);
    const uint* CW1u = (const uint*)(bfa + OFF_CW1);
    float* outp = (float*)d_out;

    hipLaunchKernelGGL(interp_convert_kernel, dim3(384 + 512), dim3(256), 0, stream,
                       image, loc, scl, pix, w0, rw, wf, cw0, crw, cw1, bfa);
    hipLaunchKernelGGL(pack_inp_kernel, dim3(128), dim3(256), 0, stream,
                       loc, scl, pix, hidden, inp2);
    hipLaunchKernelGGL((layer_gemm<256, 0>), dim3(16), dim3(1024), 0, stream,
                       inp2, W0u, 256, 256, b0, (const float*)nullptr, h0f, 256, h0p);
    hipLaunchKernelGGL((layer_gemm<128, 1>), dim3(16), dim3(1024), 0, stream,
                       h0p, RWu, 256, 256, rb, h0f, h1f, 256, h1p);
    hipLaunchKernelGGL((layer_gemm<128, 1>), dim3(16), dim3(1024), 0, stream,
                       h1p, RWu + 32768, 256, 256, rb + 256, h1f, h0f, 256, h0p);
    hipLaunchKernelGGL((layer_gemm<128, 1>), dim3(16), dim3(1024), 0, stream,
                       h0p, RWu + 65536, 256, 256, rb + 512, h0f, h1f, 256, h1p);
    hipLaunchKernelGGL((layer_gemm<128, 1>), dim3(16), dim3(1024), 0, stream,
                       h1p, RWu + 98304, 256, 256, rb + 768, h1f, h0f, 256, h0p);
    hipLaunchKernelGGL((layer_gemm<128, 2>), dim3(17), dim3(1024), 0, stream,
                       h0p, WFu, 260, 259, bf, (const float*)nullptr, wfo, 260, (uint*)nullptr);
    hipLaunchKernelGGL(update_kernel, dim3(128), dim3(256), 0, stream,
                       loc, scl, hidden, wfo, nhf, nhp, outp);
    hipLaunchKernelGGL((layer_gemm<128, 1>), dim3(16), dim3(1024), 0, stream,
                       nhp, CW0u, 256, 256, cb0, (const float*)nullptr, c0f, 256, c0p);
    hipLaunchKernelGGL((layer_gemm<128, 1>), dim3(16), dim3(1024), 0, stream,
                       c0p, CRWu, 256, 256, crb, c0f, c1f, 256, c1p);
    hipLaunchKernelGGL((layer_gemm<128, 0>), dim3(64), dim3(1024), 0, stream,
                       c1p, CW1u, 1024, 1000, cb1, (const float*)nullptr, lg, 1024, (uint*)nullptr);
    hipLaunchKernelGGL(softmax_kernel, dim3(128), dim3(1024), 0, stream,
                       lg, outp);
}

// Round 16
// 71.667 us; speedup vs baseline: 1.8071x; 1.8071x over previous
//
#include <hip/hip_runtime.h>
#include <math.h>

#define BB 128
#define OUTROW 1259   // 2+1+256+1000

typedef float vf4 __attribute__((ext_vector_type(4)));

// ---------------- bf16 helpers ----------------
__device__ __forceinline__ ushort f2b(float x) {
    unsigned u = __float_as_uint(x);
    unsigned r = (u + 0x7FFFu + ((u >> 16) & 1u)) >> 16;   // RNE
    return (ushort)r;
}
__device__ __forceinline__ uint pack2(float lo, float hi) {
    return (uint)f2b(lo) | ((uint)f2b(hi) << 16);
}
// D = a.bf16[0]*b.bf16[0] + a.bf16[1]*b.bf16[1] + c   (f32 accumulate)
__device__ __forceinline__ float dot2bf(uint a, uint b, float c) {
    float d;
    asm("v_dot2_f32_bf16 %0, %1, %2, %3" : "=v"(d) : "v"(a), "v"(b), "v"(c));
    return d;
}

// bf16 arena: pair-interleaved layout W2[k/2][col][2] (ushort offsets)
#define OFF_W0   0u        // 240 kp * 512          = 122880  (k padded 451->480)
#define OFF_RW   122880u   // 4 layers * 128kp*512  = 262144
#define OFF_CW0  385024u   // 128*512               = 65536
#define OFF_CRW  450560u   // 128*512               = 65536
#define OFF_WF   516096u   // 128 kp * 520 (260c)   = 66560   (col 259 zero-pad)
#define OFF_CW1  582656u   // 128 kp * 2000 (1000c) = 256000
#define N_TOT    838656u   // ushorts = 419328 uints

__device__ __forceinline__ void dirichlet_ab(float t, float& A, float& Bv) {
    float r = t - rintf(t);
    float s256 = sinpif(256.0f * r);
    Bv = s256 * (1.0f / 256.0f);
    if (fabsf(r) < 1e-6f) {
        A = 1.0f;
    } else {
        float sp = sinpif(r), cp = cospif(r);
        A = Bv * cp / sp;
    }
}

// blocks 0..383: NUDFT interp (one per (b,c)); blocks 384+: bf16 pair-convert.
// Arena writes are NON-TEMPORAL: lines must land clean in L3, not dirty in
// the writer XCD's L2 (cross-XCD dirty-line forwarding theory).
__global__ __launch_bounds__(256) void interp_convert_kernel(
    const float* __restrict__ image, const float* __restrict__ loc,
    const float* __restrict__ scl, float* __restrict__ pix,
    const float* __restrict__ w0, const float* __restrict__ rw,
    const float* __restrict__ wf, const float* __restrict__ cw0,
    const float* __restrict__ crw, const float* __restrict__ cw1,
    ushort* __restrict__ bfa)
{
    __shared__ float U[256 * 16];
    __shared__ float V[16 * 260];
    __shared__ float T[16 * 260];

    int bid = blockIdx.x;
    int tid = threadIdx.x;

    if (bid >= 384) {
        unsigned g = (unsigned)(bid - 384) * 256u + (unsigned)tid;
        for (unsigned j = g; j < N_TOT; j += 512u * 256u) {
            ushort v;
            if (j < 122880u) {                     // w0: C=256, 451 real rows
                unsigned kp = j >> 9, r = j & 511u, c = r >> 1, k = 2u*kp + (r & 1u);
                v = (k < 451u) ? f2b(w0[k * 256u + c]) : (ushort)0;
            } else if (j < 385024u) {              // rw
                unsigned jj = j - 122880u;
                unsigned kp = jj >> 9, r = jj & 511u, c = r >> 1, k = 2u*kp + (r & 1u);
                v = f2b(rw[k * 256u + c]);
            } else if (j < 450560u) {              // cw0
                unsigned jj = j - 385024u;
                unsigned kp = jj >> 9, r = jj & 511u, c = r >> 1, k = 2u*kp + (r & 1u);
                v = f2b(cw0[k * 256u + c]);
            } else if (j < 516096u) {              // crw
                unsigned jj = j - 450560u;
                unsigned kp = jj >> 9, r = jj & 511u, c = r >> 1, k = 2u*kp + (r & 1u);
                v = f2b(crw[k * 256u + c]);
            } else if (j < 582656u) {              // wf: pitch 260 cols, 259 real
                unsigned jj = j - 516096u;
                unsigned kp = jj / 520u, r = jj - kp * 520u, c = r >> 1, k = 2u*kp + (r & 1u);
                v = (c < 259u) ? f2b(wf[k * 259u + c]) : (ushort)0;
            } else {                               // cw1: 1000 cols
                unsigned jj = j - 582656u;
                unsigned kp = jj / 2000u, r = jj - kp * 2000u, c = r >> 1, k = 2u*kp + (r & 1u);
                v = f2b(cw1[k * 1000u + c]);
            }
            __builtin_nontemporal_store(v, &bfa[j]);
        }
        return;
    }

    int b = bid / 3, c = bid % 3;
    float l0 = loc[2 * b], l1 = loc[2 * b + 1], sc = scl[b];

    {
        int p = tid;
        float tp = (float)p * (1.0f / 256.0f);
        #pragma unroll
        for (int iy = 0; iy < 8; ++iy) {
            float A, Bv;
            float y = ((float)iy * 0.125f - l0) * sc;
            dirichlet_ab(y - tp, A, Bv);
            int w = iy >> 1, o = iy & 1;
            U[p * 16 + w * 4 + o] = A;
            U[p * 16 + w * 4 + 2 + o] = Bv;
            float x = ((float)iy * 0.125f - l1) * sc;
            dirichlet_ab(x - tp, A, Bv);
            V[iy * 260 + p] = A;
            V[(8 + iy) * 260 + p] = Bv;
        }
    }
    __syncthreads();

    int wave = tid >> 6, lane = tid & 63;
    const float* img = image + (size_t)(b * 3 + c) * 65536 + lane * 4;

    float aA0[4] = {0, 0, 0, 0}, aA1[4] = {0, 0, 0, 0};
    float aB0[4] = {0, 0, 0, 0}, aB1[4] = {0, 0, 0, 0};
    #pragma unroll 4
    for (int p = 0; p < 256; ++p) {
        vf4 v = __builtin_nontemporal_load((const vf4*)(img + p * 256));
        const float4 u = *(const float4*)(&U[p * 16 + wave * 4]);
        aA0[0] += u.x * v[0]; aA0[1] += u.x * v[1]; aA0[2] += u.x * v[2]; aA0[3] += u.x * v[3];
        aA1[0] += u.y * v[0]; aA1[1] += u.y * v[1]; aA1[2] += u.y * v[2]; aA1[3] += u.y * v[3];
        aB0[0] += u.z * v[0]; aB0[1] += u.z * v[1]; aB0[2] += u.z * v[2]; aB0[3] += u.z * v[3];
        aB1[0] += u.w * v[0]; aB1[1] += u.w * v[1]; aB1[2] += u.w * v[2]; aB1[3] += u.w * v[3];
    }
    int iy0 = wave * 2;
    int q0 = lane * 4;
    #pragma unroll
    for (int j = 0; j < 4; ++j) {
        T[iy0 * 260 + q0 + j]       = aA0[j];
        T[(iy0 + 1) * 260 + q0 + j] = aA1[j];
        T[(8 + iy0) * 260 + q0 + j]     = aB0[j];
        T[(8 + iy0 + 1) * 260 + q0 + j] = aB1[j];
    }
    __syncthreads();

    int n = tid >> 2, sub = tid & 3;
    int iy = n >> 3, ix = n & 7;
    float s = 0.f;
    #pragma unroll 8
    for (int i = 0; i < 64; ++i) {
        int q = sub + 4 * i;
        s += T[iy * 260 + q] * V[ix * 260 + q] - T[(8 + iy) * 260 + q] * V[(8 + ix) * 260 + q];
    }
    s += __shfl_xor(s, 1);
    s += __shfl_xor(s, 2);
    if (sub == 0) pix[(b * 64 + n) * 3 + c] = s;
}

// Monolithic per-row MLP (blocks 0..127) + L2-warmer blocks (128..255).
__global__ __launch_bounds__(1024, 1) void mlp_fused(
    const float* __restrict__ loc, const float* __restrict__ scl,
    const float* __restrict__ hidden, const float* __restrict__ pix,
    const ushort* __restrict__ bfa,
    const float* __restrict__ b0, const float* __restrict__ rb,
    const float* __restrict__ bf, const float* __restrict__ cb0,
    const float* __restrict__ crb, const float* __restrict__ cb1,
    float* __restrict__ out, float* __restrict__ sink)
{
    __shared__ float s_in[480];
    __shared__ float s_h[256];
    __shared__ float s_c[256];
    __shared__ float s_o[260];
    __shared__ float s_part[16 * 260];
    __shared__ float s_lg[1024];
    __shared__ uint  s_in2[240];
    __shared__ uint  s_hb2[128];
    __shared__ uint  s_cb2[128];
    __shared__ float s_b0[256], s_rb[1024], s_bf[260], s_cb0[256], s_crb[256], s_cb1[1000];
    __shared__ float s_red[32];

    int bid = blockIdx.x, tid = threadIdx.x;

    if (bid >= BB) {
        // ---------- L2 warmer ----------
        const uint* A = (const uint*)bfa;            // 419328 uints
        int w = bid - BB;
        int slice = w >> 3;                          // 0..15
        unsigned SL = 26208u;                        // 419328/16
        unsigned lo = slice * SL, hi = lo + SL;
        float acc = 0.f;
        for (int it = 0; it < 16; ++it) {
            for (unsigned i = lo + tid * 4u; i + 3u < hi; i += 4096u) {
                uint4 v = *(const uint4*)(A + i);
                acc += (float)(v.x ^ v.y ^ v.z ^ v.w);
            }
        }
        if (acc == 1.0e30f) sink[0] = acc;           // never true; keeps loads live
        return;
    }

    int b = bid;
    int jg = tid & 63, sub = tid >> 6;
    int j4 = jg * 4;
    float* orow = out + (size_t)b * OUTROW;

    // ---- stage inputs + biases ----
    if (tid < 2) s_in[tid] = loc[2 * b + tid];
    if (tid == 2) s_in[2] = scl[b];
    if (tid >= 256 && tid < 448) s_in[3 + (tid - 256)] = pix[b * 192 + (tid - 256)];
    if (tid >= 512 && tid < 768) s_in[195 + (tid - 512)] = hidden[b * 256 + (tid - 512)];
    if (tid >= 768 && tid < 797) s_in[451 + (tid - 768)] = 0.f;   // pad 451..479
    if (tid < 256) s_b0[tid] = b0[tid];
    s_rb[tid] = rb[tid];
    if (tid < 259) s_bf[tid] = bf[tid];
    if (tid >= 256 && tid < 512) s_cb0[tid - 256] = cb0[tid - 256];
    if (tid >= 512 && tid < 768) s_crb[tid - 512] = crb[tid - 512];
    if (tid < 1000) s_cb1[tid] = cb1[tid];
    __syncthreads();
    if (tid < 240) s_in2[tid] = pack2(s_in[2 * tid], s_in[2 * tid + 1]);
    __syncthreads();

    const ushort* w0b  = bfa + OFF_W0;
    const ushort* rwb  = bfa + OFF_RW;
    const ushort* cw0b = bfa + OFF_CW0;
    const ushort* crwb = bfa + OFF_CRW;
    const ushort* wfb  = bfa + OFF_WF;
    const ushort* cw1b = bfa + OFF_CW1;

    // ---- h0 = inp @ w0 + b0 (240 k-pairs, 15 per sub) ----
    {
        uint4 wv[15]; uint hv[15];
        #pragma unroll
        for (int t = 0; t < 15; ++t)
            wv[t] = *(const uint4*)(w0b + (size_t)(sub + 16 * t) * 512 + jg * 8);
        #pragma unroll
        for (int t = 0; t < 15; ++t) hv[t] = s_in2[sub + 16 * t];
        vf4 a = {0.f, 0.f, 0.f, 0.f};
        #pragma unroll
        for (int t = 0; t < 15; ++t) {
            a[0] = dot2bf(wv[t].x, hv[t], a[0]);
            a[1] = dot2bf(wv[t].y, hv[t], a[1]);
            a[2] = dot2bf(wv[t].z, hv[t], a[2]);
            a[3] = dot2bf(wv[t].w, hv[t], a[3]);
        }
        *(vf4*)(&s_part[sub * 256 + j4]) = a;
    }
    __syncthreads();
    if (tid < 256) {
        float v = s_b0[tid];
        #pragma unroll
        for (int s = 0; s < 16; ++s) v += s_part[s * 256 + tid];
        s_h[tid] = v;
        float v2 = __shfl_xor(v, 1);
        if (!(tid & 1)) s_hb2[tid >> 1] = pack2(v, v2);
    }
    __syncthreads();

    // ---- 4 residual layers: h = relu(h@rw + rb + h) ----
    #pragma unroll 1
    for (int L = 0; L < 4; ++L) {
        const ushort* W = rwb + (size_t)L * 65536;
        {
            uint4 wv[8]; uint hv[8];
            #pragma unroll
            for (int t = 0; t < 8; ++t)
                wv[t] = *(const uint4*)(W + (size_t)(sub + 16 * t) * 512 + jg * 8);
            #pragma unroll
            for (int t = 0; t < 8; ++t) hv[t] = s_hb2[sub + 16 * t];
            vf4 a = {0.f, 0.f, 0.f, 0.f};
            #pragma unroll
            for (int t = 0; t < 8; ++t) {
                a[0] = dot2bf(wv[t].x, hv[t], a[0]);
                a[1] = dot2bf(wv[t].y, hv[t], a[1]);
                a[2] = dot2bf(wv[t].z, hv[t], a[2]);
                a[3] = dot2bf(wv[t].w, hv[t], a[3]);
            }
            *(vf4*)(&s_part[sub * 256 + j4]) = a;
        }
        __syncthreads();
        if (tid < 256) {
            float v = s_rb[L * 256 + tid] + s_h[tid];
            #pragma unroll
            for (int s = 0; s < 16; ++s) v += s_part[s * 256 + tid];
            v = fmaxf(v, 0.f);
            s_h[tid] = v;
            float v2 = __shfl_xor(v, 1);
            if (!(tid & 1)) s_hb2[tid >> 1] = pack2(v, v2);
        }
        __syncthreads();
    }

    // ---- o = tanh(h @ wf + bf) (260-col padded) ----
    {
        uint4 wv[8]; uint hv[8];
        #pragma unroll
        for (int t = 0; t < 8; ++t)
            wv[t] = *(const uint4*)(wfb + (size_t)(sub + 16 * t) * 520 + jg * 8);
        #pragma unroll
        for (int t = 0; t < 8; ++t) hv[t] = s_hb2[sub + 16 * t];
        vf4 a = {0.f, 0.f, 0.f, 0.f};
        #pragma unroll
        for (int t = 0; t < 8; ++t) {
            a[0] = dot2bf(wv[t].x, hv[t], a[0]);
            a[1] = dot2bf(wv[t].y, hv[t], a[1]);
            a[2] = dot2bf(wv[t].z, hv[t], a[2]);
            a[3] = dot2bf(wv[t].w, hv[t], a[3]);
        }
        *(vf4*)(&s_part[sub * 260 + j4]) = a;
        if (jg < 4) {                                   // tail cols 256..259
            float e = 0.f;
            #pragma unroll
            for (int t = 0; t < 8; ++t) {
                uint w = *(const uint*)(wfb + (size_t)(sub + 16 * t) * 520 + 512 + jg * 2);
                e = dot2bf(w, hv[t], e);
            }
            s_part[sub * 260 + 256 + jg] = e;
        }
    }
    __syncthreads();
    if (tid < 259) {
        float v = s_bf[tid];
        #pragma unroll
        for (int s = 0; s < 16; ++s) v += s_part[s * 260 + tid];
        s_o[tid] = tanhf(v);
    }
    __syncthreads();

    // ---- state update + direct outputs ----
    if (tid < 256) {
        float nh = s_in[195 + tid] + s_o[3 + tid];
        orow[3 + tid] = nh;
        s_h[tid] = nh;
        float v2 = __shfl_xor(nh, 1);
        if (!(tid & 1)) s_hb2[tid >> 1] = pack2(nh, v2);
    }
    if (tid == 256) orow[0] = s_in[0] + s_o[0];
    if (tid == 257) orow[1] = s_in[1] + s_o[1];
    if (tid == 258) orow[2] = s_in[2] + s_o[2];
    __syncthreads();

    // ---- c0 = relu(nh @ cw0 + cb0) ----
    {
        uint4 wv[8]; uint hv[8];
        #pragma unroll
        for (int t = 0; t < 8; ++t)
            wv[t] = *(const uint4*)(cw0b + (size_t)(sub + 16 * t) * 512 + jg * 8);
        #pragma unroll
        for (int t = 0; t < 8; ++t) hv[t] = s_hb2[sub + 16 * t];
        vf4 a = {0.f, 0.f, 0.f, 0.f};
        #pragma unroll
        for (int t = 0; t < 8; ++t) {
            a[0] = dot2bf(wv[t].x, hv[t], a[0]);
            a[1] = dot2bf(wv[t].y, hv[t], a[1]);
            a[2] = dot2bf(wv[t].z, hv[t], a[2]);
            a[3] = dot2bf(wv[t].w, hv[t], a[3]);
        }
        *(vf4*)(&s_part[sub * 256 + j4]) = a;
    }
    __syncthreads();
    if (tid < 256) {
        float v = s_cb0[tid];
        #pragma unroll
        for (int s = 0; s < 16; ++s) v += s_part[s * 256 + tid];
        v = fmaxf(v, 0.f);
        s_c[tid] = v;
        float v2 = __shfl_xor(v, 1);
        if (!(tid & 1)) s_cb2[tid >> 1] = pack2(v, v2);
    }
    __syncthreads();

    // ---- c1 = relu(c0 @ crw + crb + c0) ----
    {
        uint4 wv[8]; uint hv[8];
        #pragma unroll
        for (int t = 0; t < 8; ++t)
            wv[t] = *(const uint4*)(crwb + (size_t)(sub + 16 * t) * 512 + jg * 8);
        #pragma unroll
        for (int t = 0; t < 8; ++t) hv[t] = s_cb2[sub + 16 * t];
        vf4 a = {0.f, 0.f, 0.f, 0.f};
        #pragma unroll
        for (int t = 0; t < 8; ++t) {
            a[0] = dot2bf(wv[t].x, hv[t], a[0]);
            a[1] = dot2bf(wv[t].y, hv[t], a[1]);
            a[2] = dot2bf(wv[t].z, hv[t], a[2]);
            a[3] = dot2bf(wv[t].w, hv[t], a[3]);
        }
        *(vf4*)(&s_part[sub * 256 + j4]) = a;
    }
    __syncthreads();
    if (tid < 256) {
        float v = s_crb[tid] + s_c[tid];
        #pragma unroll
        for (int s = 0; s < 16; ++s) v += s_part[s * 256 + tid];
        v = fmaxf(v, 0.f);
        float v2 = __shfl_xor(v, 1);
        if (!(tid & 1)) s_cb2[tid >> 1] = pack2(v, v2);
    }
    __syncthreads();

    // ---- logits pass 1: cols 0..511 (8-way kp split) ----
    int jg8 = tid & 127, sub8 = tid >> 7;
    int c4 = jg8 * 4;
    {
        uint4 wv[16]; uint hv[16];
        #pragma unroll
        for (int t = 0; t < 16; ++t)
            wv[t] = *(const uint4*)(cw1b + (size_t)(sub8 + 8 * t) * 2000 + c4 * 2);
        #pragma unroll
        for (int t = 0; t < 16; ++t) hv[t] = s_cb2[sub8 + 8 * t];
        vf4 a = {0.f, 0.f, 0.f, 0.f};
        #pragma unroll
        for (int t = 0; t < 16; ++t) {
            a[0] = dot2bf(wv[t].x, hv[t], a[0]);
            a[1] = dot2bf(wv[t].y, hv[t], a[1]);
            a[2] = dot2bf(wv[t].z, hv[t], a[2]);
            a[3] = dot2bf(wv[t].w, hv[t], a[3]);
        }
        *(vf4*)(&s_part[sub8 * 512 + c4]) = a;
    }
    __syncthreads();
    if (tid < 512) {
        float v = s_cb1[tid];
        #pragma unroll
        for (int s = 0; s < 8; ++s) v += s_part[s * 512 + tid];
        s_lg[tid] = v;
    }
    __syncthreads();

    // ---- logits pass 2: cols 512..999 ----
    {
        vf4 a = {0.f, 0.f, 0.f, 0.f};
        if (jg8 < 122) {
            uint4 wv[16]; uint hv[16];
            #pragma unroll
            for (int t = 0; t < 16; ++t)
                wv[t] = *(const uint4*)(cw1b + (size_t)(sub8 + 8 * t) * 2000 + (512 + c4) * 2);
            #pragma unroll
            for (int t = 0; t < 16; ++t) hv[t] = s_cb2[sub8 + 8 * t];
            #pragma unroll
            for (int t = 0; t < 16; ++t) {
                a[0] = dot2bf(wv[t].x, hv[t], a[0]);
                a[1] = dot2bf(wv[t].y, hv[t], a[1]);
                a[2] = dot2bf(wv[t].z, hv[t], a[2]);
                a[3] = dot2bf(wv[t].w, hv[t], a[3]);
            }
        }
        *(vf4*)(&s_part[sub8 * 512 + c4]) = a;
    }
    __syncthreads();
    if (tid < 488) {
        float v = s_cb1[512 + tid];
        #pragma unroll
        for (int s = 0; s < 8; ++s) v += s_part[s * 512 + tid];
        s_lg[512 + tid] = v;
    }
    __syncthreads();

    // ---- softmax over 1000 ----
    float lgv = (tid < 1000) ? s_lg[tid] : -1e30f;
    int lane = tid & 63, wid = tid >> 6;
    float m = lgv;
    #pragma unroll
    for (int off = 1; off < 64; off <<= 1) m = fmaxf(m, __shfl_xor(m, off));
    if (lane == 0) s_red[wid] = m;
    __syncthreads();
    m = s_red[0];
    #pragma unroll
    for (int w = 1; w < 16; ++w) m = fmaxf(m, s_red[w]);

    float e = (tid < 1000) ? expf(lgv - m) : 0.f;
    float lsum = e;
    #pragma unroll
    for (int off = 1; off < 64; off <<= 1) lsum += __shfl_xor(lsum, off);
    if (lane == 0) s_red[16 + wid] = lsum;
    __syncthreads();
    float total = 0.f;
    #pragma unroll
    for (int w = 0; w < 16; ++w) total += s_red[16 + w];

    if (tid < 1000) orow[259 + tid] = e / total;
}

extern "C" void kernel_launch(void* const* d_in, const int* in_sizes, int n_in,
                              void* d_out, int out_size, void* d_ws, size_t ws_size,
                              hipStream_t stream) {
    const float* image  = (const float*)d_in[0];
    const float* loc    = (const float*)d_in[1];
    const float* scl    = (const float*)d_in[2];
    const float* hidden = (const float*)d_in[3];
    const float* w0  = (const float*)d_in[4];
    const float* b0  = (const float*)d_in[5];
    const float* rw  = (const float*)d_in[6];
    const float* rb  = (const float*)d_in[7];
    const float* wf  = (const float*)d_in[8];
    const float* bf  = (const float*)d_in[9];
    const float* cw0 = (const float*)d_in[10];
    const float* cb0 = (const float*)d_in[11];
    const float* crw = (const float*)d_in[12];
    const float* crb = (const float*)d_in[13];
    const float* cw1 = (const float*)d_in[14];
    const float* cb1 = (const float*)d_in[15];

    float* ws   = (float*)d_ws;
    float* pix  = ws;                          // 24576 floats
    ushort* bfa = (ushort*)(ws + 24576);       // 838656 ushorts (~1.68 MB)
    float* sink = ws + 24576 + 419328 + 8;

    hipLaunchKernelGGL(interp_convert_kernel, dim3(384 + 512), dim3(256), 0, stream,
                       image, loc, scl, pix, w0, rw, wf, cw0, crw, cw1, bfa);
    hipLaunchKernelGGL(mlp_fused, dim3(256), dim3(1024), 0, stream,
                       loc, scl, hidden, pix, bfa,
                       b0, rb, bf, cb0, crb, cb1, (float*)d_out, sink);
}

// Round 17
// 71.483 us; speedup vs baseline: 1.8117x; 1.0026x over previous
//
#include <hip/hip_runtime.h>
#include <math.h>

#define BB 128
#define OUTROW 1259   // 2+1+256+1000

typedef float vf4 __attribute__((ext_vector_type(4)));

// ---------------- bf16 helpers ----------------
__device__ __forceinline__ ushort f2b(float x) {
    unsigned u = __float_as_uint(x);
    unsigned r = (u + 0x7FFFu + ((u >> 16) & 1u)) >> 16;   // RNE
    return (ushort)r;
}
__device__ __forceinline__ uint pack2(float lo, float hi) {
    return (uint)f2b(lo) | ((uint)f2b(hi) << 16);
}
__device__ __forceinline__ float dot2bf(uint a, uint b, float c) {
    float d;
    asm("v_dot2_f32_bf16 %0, %1, %2, %3" : "=v"(d) : "v"(a), "v"(b), "v"(c));
    return d;
}

// bf16 arena: pair-interleaved layout W2[k/2][col][2] (ushort offsets)
#define OFF_W0   0u        // 240 kp * 512          = 122880  (k padded 451->480)
#define OFF_RW   122880u   // 4 layers * 128kp*512  = 262144
#define OFF_CW0  385024u   // 128*512               = 65536
#define OFF_CRW  450560u   // 128*512               = 65536
#define OFF_WF   516096u   // 128 kp * 520 (260c)   = 66560   (col 259 zero-pad)
#define OFF_CW1  582656u   // 128 kp * 2000 (1000c) = 256000
#define N_TOT    838656u   // ushorts = 419328 uints

// prefetch load of 8 uint4 into named regs (no arrays -> no spill risk)
#define LOADW8(V, BASE, STR) do { \
    V##0 = *(const uint4*)((BASE) + (size_t)(sub +   0) * (STR) + jg * 8); \
    V##1 = *(const uint4*)((BASE) + (size_t)(sub +  16) * (STR) + jg * 8); \
    V##2 = *(const uint4*)((BASE) + (size_t)(sub +  32) * (STR) + jg * 8); \
    V##3 = *(const uint4*)((BASE) + (size_t)(sub +  48) * (STR) + jg * 8); \
    V##4 = *(const uint4*)((BASE) + (size_t)(sub +  64) * (STR) + jg * 8); \
    V##5 = *(const uint4*)((BASE) + (size_t)(sub +  80) * (STR) + jg * 8); \
    V##6 = *(const uint4*)((BASE) + (size_t)(sub +  96) * (STR) + jg * 8); \
    V##7 = *(const uint4*)((BASE) + (size_t)(sub + 112) * (STR) + jg * 8); \
} while (0)

#define DOT1(V, H) do { \
    a[0] = dot2bf(V.x, H, a[0]); a[1] = dot2bf(V.y, H, a[1]); \
    a[2] = dot2bf(V.z, H, a[2]); a[3] = dot2bf(V.w, H, a[3]); \
} while (0)

#define DOT8(V, SRC) do { \
    uint h_; \
    h_ = (SRC)[sub +   0]; DOT1(V##0, h_); \
    h_ = (SRC)[sub +  16]; DOT1(V##1, h_); \
    h_ = (SRC)[sub +  32]; DOT1(V##2, h_); \
    h_ = (SRC)[sub +  48]; DOT1(V##3, h_); \
    h_ = (SRC)[sub +  64]; DOT1(V##4, h_); \
    h_ = (SRC)[sub +  80]; DOT1(V##5, h_); \
    h_ = (SRC)[sub +  96]; DOT1(V##6, h_); \
    h_ = (SRC)[sub + 112]; DOT1(V##7, h_); \
} while (0)

__device__ __forceinline__ void dirichlet_ab(float t, float& A, float& Bv) {
    float r = t - rintf(t);
    float s256 = sinpif(256.0f * r);
    Bv = s256 * (1.0f / 256.0f);
    if (fabsf(r) < 1e-6f) {
        A = 1.0f;
    } else {
        float sp = sinpif(r), cp = cospif(r);
        A = Bv * cp / sp;
    }
}

// blocks 0..383: NUDFT interp (one per (b,c)); blocks 384+: bf16 pair-convert.
__global__ __launch_bounds__(256) void interp_convert_kernel(
    const float* __restrict__ image, const float* __restrict__ loc,
    const float* __restrict__ scl, float* __restrict__ pix,
    const float* __restrict__ w0, const float* __restrict__ rw,
    const float* __restrict__ wf, const float* __restrict__ cw0,
    const float* __restrict__ crw, const float* __restrict__ cw1,
    ushort* __restrict__ bfa)
{
    __shared__ float U[256 * 16];
    __shared__ float V[16 * 260];
    __shared__ float T[16 * 260];

    int bid = blockIdx.x;
    int tid = threadIdx.x;

    if (bid >= 384) {
        unsigned g = (unsigned)(bid - 384) * 256u + (unsigned)tid;
        for (unsigned j = g; j < N_TOT; j += 512u * 256u) {
            ushort v;
            if (j < 122880u) {
                unsigned kp = j >> 9, r = j & 511u, c = r >> 1, k = 2u*kp + (r & 1u);
                v = (k < 451u) ? f2b(w0[k * 256u + c]) : (ushort)0;
            } else if (j < 385024u) {
                unsigned jj = j - 122880u;
                unsigned kp = jj >> 9, r = jj & 511u, c = r >> 1, k = 2u*kp + (r & 1u);
                v = f2b(rw[k * 256u + c]);
            } else if (j < 450560u) {
                unsigned jj = j - 385024u;
                unsigned kp = jj >> 9, r = jj & 511u, c = r >> 1, k = 2u*kp + (r & 1u);
                v = f2b(cw0[k * 256u + c]);
            } else if (j < 516096u) {
                unsigned jj = j - 450560u;
                unsigned kp = jj >> 9, r = jj & 511u, c = r >> 1, k = 2u*kp + (r & 1u);
                v = f2b(crw[k * 256u + c]);
            } else if (j < 582656u) {
                unsigned jj = j - 516096u;
                unsigned kp = jj / 520u, r = jj - kp * 520u, c = r >> 1, k = 2u*kp + (r & 1u);
                v = (c < 259u) ? f2b(wf[k * 259u + c]) : (ushort)0;
            } else {
                unsigned jj = j - 582656u;
                unsigned kp = jj / 2000u, r = jj - kp * 2000u, c = r >> 1, k = 2u*kp + (r & 1u);
                v = f2b(cw1[k * 1000u + c]);
            }
            __builtin_nontemporal_store(v, &bfa[j]);
        }
        return;
    }

    int b = bid / 3, c = bid % 3;
    float l0 = loc[2 * b], l1 = loc[2 * b + 1], sc = scl[b];

    {
        int p = tid;
        float tp = (float)p * (1.0f / 256.0f);
        #pragma unroll
        for (int iy = 0; iy < 8; ++iy) {
            float A, Bv;
            float y = ((float)iy * 0.125f - l0) * sc;
            dirichlet_ab(y - tp, A, Bv);
            int w = iy >> 1, o = iy & 1;
            U[p * 16 + w * 4 + o] = A;
            U[p * 16 + w * 4 + 2 + o] = Bv;
            float x = ((float)iy * 0.125f - l1) * sc;
            dirichlet_ab(x - tp, A, Bv);
            V[iy * 260 + p] = A;
            V[(8 + iy) * 260 + p] = Bv;
        }
    }
    __syncthreads();

    int wave = tid >> 6, lane = tid & 63;
    const float* img = image + (size_t)(b * 3 + c) * 65536 + lane * 4;

    float aA0[4] = {0, 0, 0, 0}, aA1[4] = {0, 0, 0, 0};
    float aB0[4] = {0, 0, 0, 0}, aB1[4] = {0, 0, 0, 0};
    #pragma unroll 4
    for (int p = 0; p < 256; ++p) {
        vf4 v = __builtin_nontemporal_load((const vf4*)(img + p * 256));
        const float4 u = *(const float4*)(&U[p * 16 + wave * 4]);
        aA0[0] += u.x * v[0]; aA0[1] += u.x * v[1]; aA0[2] += u.x * v[2]; aA0[3] += u.x * v[3];
        aA1[0] += u.y * v[0]; aA1[1] += u.y * v[1]; aA1[2] += u.y * v[2]; aA1[3] += u.y * v[3];
        aB0[0] += u.z * v[0]; aB0[1] += u.z * v[1]; aB0[2] += u.z * v[2]; aB0[3] += u.z * v[3];
        aB1[0] += u.w * v[0]; aB1[1] += u.w * v[1]; aB1[2] += u.w * v[2]; aB1[3] += u.w * v[3];
    }
    int iy0 = wave * 2;
    int q0 = lane * 4;
    #pragma unroll
    for (int j = 0; j < 4; ++j) {
        T[iy0 * 260 + q0 + j]       = aA0[j];
        T[(iy0 + 1) * 260 + q0 + j] = aA1[j];
        T[(8 + iy0) * 260 + q0 + j]     = aB0[j];
        T[(8 + iy0 + 1) * 260 + q0 + j] = aB1[j];
    }
    __syncthreads();

    int n = tid >> 2, sub = tid & 3;
    int iy = n >> 3, ix = n & 7;
    float s = 0.f;
    #pragma unroll 8
    for (int i = 0; i < 64; ++i) {
        int q = sub + 4 * i;
        s += T[iy * 260 + q] * V[ix * 260 + q] - T[(8 + iy) * 260 + q] * V[(8 + ix) * 260 + q];
    }
    s += __shfl_xor(s, 1);
    s += __shfl_xor(s, 2);
    if (sub == 0) pix[(b * 64 + n) * 3 + c] = s;
}

// Monolithic per-row MLP (blocks 0..127) + L2-warmer blocks (128..255).
// Cross-layer weight prefetch: named uint4 double-buffer A/P, statically
// alternated; next layer's 8 loads issued BEFORE current layer's compute.
__global__ __launch_bounds__(1024, 1) void mlp_fused(
    const float* __restrict__ loc, const float* __restrict__ scl,
    const float* __restrict__ hidden, const float* __restrict__ pix,
    const ushort* __restrict__ bfa,
    const float* __restrict__ b0, const float* __restrict__ rb,
    const float* __restrict__ bf, const float* __restrict__ cb0,
    const float* __restrict__ crb, const float* __restrict__ cb1,
    float* __restrict__ out, float* __restrict__ sink)
{
    __shared__ float s_in[480];
    __shared__ float s_h[256];
    __shared__ float s_c[256];
    __shared__ float s_o[260];
    __shared__ float s_part[16 * 260];
    __shared__ float s_lg[1024];
    __shared__ uint  s_in2[240];
    __shared__ uint  s_hb2[128];
    __shared__ uint  s_cb2[128];
    __shared__ float s_b0[256], s_rb[1024], s_bf[260], s_cb0[256], s_crb[256], s_cb1[1000];
    __shared__ float s_red[32];

    int bid = blockIdx.x, tid = threadIdx.x;

    if (bid >= BB) {
        // ---------- L2 warmer ----------
        const uint* A = (const uint*)bfa;            // 419328 uints
        int w = bid - BB;
        int slice = w >> 3;                          // 0..15
        unsigned SL = 26208u;
        unsigned lo = slice * SL, hi = lo + SL;
        float acc = 0.f;
        for (int it = 0; it < 16; ++it) {
            for (unsigned i = lo + tid * 4u; i + 3u < hi; i += 4096u) {
                uint4 v = *(const uint4*)(A + i);
                acc += (float)(v.x ^ v.y ^ v.z ^ v.w);
            }
        }
        if (acc == 1.0e30f) sink[0] = acc;
        return;
    }

    int b = bid;
    int jg = tid & 63, sub = tid >> 6;
    int j4 = jg * 4;
    float* orow = out + (size_t)b * OUTROW;

    uint4 A0, A1, A2, A3, A4, A5, A6, A7;    // prefetch buffer A
    uint4 P0, P1, P2, P3, P4, P5, P6, P7;    // prefetch buffer P

    // ---- stage inputs + biases ----
    if (tid < 2) s_in[tid] = loc[2 * b + tid];
    if (tid == 2) s_in[2] = scl[b];
    if (tid >= 256 && tid < 448) s_in[3 + (tid - 256)] = pix[b * 192 + (tid - 256)];
    if (tid >= 512 && tid < 768) s_in[195 + (tid - 512)] = hidden[b * 256 + (tid - 512)];
    if (tid >= 768 && tid < 797) s_in[451 + (tid - 768)] = 0.f;
    if (tid < 256) s_b0[tid] = b0[tid];
    s_rb[tid] = rb[tid];
    if (tid < 259) s_bf[tid] = bf[tid];
    if (tid >= 256 && tid < 512) s_cb0[tid - 256] = cb0[tid - 256];
    if (tid >= 512 && tid < 768) s_crb[tid - 512] = crb[tid - 512];
    if (tid < 1000) s_cb1[tid] = cb1[tid];
    __syncthreads();
    if (tid < 240) s_in2[tid] = pack2(s_in[2 * tid], s_in[2 * tid + 1]);
    __syncthreads();

    const ushort* w0b  = bfa + OFF_W0;
    const ushort* rwb  = bfa + OFF_RW;
    const ushort* cw0b = bfa + OFF_CW0;
    const ushort* crwb = bfa + OFF_CRW;
    const ushort* wfb  = bfa + OFF_WF;
    const ushort* cw1b = bfa + OFF_CW1;

    // ---- h0 = inp @ w0 + b0 (240 kp = 15 per sub), two sequential halves ----
    {
        vf4 a = {0.f, 0.f, 0.f, 0.f};
        {
            uint4 wv[8]; uint hv[8];
            #pragma unroll
            for (int t = 0; t < 8; ++t)
                wv[t] = *(const uint4*)(w0b + (size_t)(sub + 16 * t) * 512 + jg * 8);
            #pragma unroll
            for (int t = 0; t < 8; ++t) hv[t] = s_in2[sub + 16 * t];
            #pragma unroll
            for (int t = 0; t < 8; ++t) {
                a[0] = dot2bf(wv[t].x, hv[t], a[0]);
                a[1] = dot2bf(wv[t].y, hv[t], a[1]);
                a[2] = dot2bf(wv[t].z, hv[t], a[2]);
                a[3] = dot2bf(wv[t].w, hv[t], a[3]);
            }
        }
        {
            uint4 wv[7]; uint hv[7];
            #pragma unroll
            for (int t = 0; t < 7; ++t)
                wv[t] = *(const uint4*)(w0b + (size_t)(sub + 16 * (t + 8)) * 512 + jg * 8);
            #pragma unroll
            for (int t = 0; t < 7; ++t) hv[t] = s_in2[sub + 16 * (t + 8)];
            #pragma unroll
            for (int t = 0; t < 7; ++t) {
                a[0] = dot2bf(wv[t].x, hv[t], a[0]);
                a[1] = dot2bf(wv[t].y, hv[t], a[1]);
                a[2] = dot2bf(wv[t].z, hv[t], a[2]);
                a[3] = dot2bf(wv[t].w, hv[t], a[3]);
            }
        }
        LOADW8(A, rwb, 512);                 // prefetch rw layer 0
        *(vf4*)(&s_part[sub * 256 + j4]) = a;
    }
    __syncthreads();
    if (tid < 256) {
        float v = s_b0[tid];
        #pragma unroll
        for (int s = 0; s < 16; ++s) v += s_part[s * 256 + tid];
        s_h[tid] = v;
        float v2 = __shfl_xor(v, 1);
        if (!(tid & 1)) s_hb2[tid >> 1] = pack2(v, v2);
    }
    __syncthreads();

    // ---- r0: compute A (rw0), prefetch P <- rw1 ----
    {
        LOADW8(P, rwb + 65536, 512);
        vf4 a = {0.f, 0.f, 0.f, 0.f};
        DOT8(A, s_hb2);
        *(vf4*)(&s_part[sub * 256 + j4]) = a;
    }
    __syncthreads();
    if (tid < 256) {
        float v = s_rb[tid] + s_h[tid];
        #pragma unroll
        for (int s = 0; s < 16; ++s) v += s_part[s * 256 + tid];
        v = fmaxf(v, 0.f);
        s_h[tid] = v;
        float v2 = __shfl_xor(v, 1);
        if (!(tid & 1)) s_hb2[tid >> 1] = pack2(v, v2);
    }
    __syncthreads();

    // ---- r1: compute P (rw1), prefetch A <- rw2 ----
    {
        LOADW8(A, rwb + 131072, 512);
        vf4 a = {0.f, 0.f, 0.f, 0.f};
        DOT8(P, s_hb2);
        *(vf4*)(&s_part[sub * 256 + j4]) = a;
    }
    __syncthreads();
    if (tid < 256) {
        float v = s_rb[256 + tid] + s_h[tid];
        #pragma unroll
        for (int s = 0; s < 16; ++s) v += s_part[s * 256 + tid];
        v = fmaxf(v, 0.f);
        s_h[tid] = v;
        float v2 = __shfl_xor(v, 1);
        if (!(tid & 1)) s_hb2[tid >> 1] = pack2(v, v2);
    }
    __syncthreads();

    // ---- r2: compute A (rw2), prefetch P <- rw3 ----
    {
        LOADW8(P, rwb + 196608, 512);
        vf4 a = {0.f, 0.f, 0.f, 0.f};
        DOT8(A, s_hb2);
        *(vf4*)(&s_part[sub * 256 + j4]) = a;
    }
    __syncthreads();
    if (tid < 256) {
        float v = s_rb[512 + tid] + s_h[tid];
        #pragma unroll
        for (int s = 0; s < 16; ++s) v += s_part[s * 256 + tid];
        v = fmaxf(v, 0.f);
        s_h[tid] = v;
        float v2 = __shfl_xor(v, 1);
        if (!(tid & 1)) s_hb2[tid >> 1] = pack2(v, v2);
    }
    __syncthreads();

    // ---- r3: compute P (rw3), prefetch A <- wf ----
    {
        LOADW8(A, wfb, 520);
        vf4 a = {0.f, 0.f, 0.f, 0.f};
        DOT8(P, s_hb2);
        *(vf4*)(&s_part[sub * 256 + j4]) = a;
    }
    __syncthreads();
    if (tid < 256) {
        float v = s_rb[768 + tid] + s_h[tid];
        #pragma unroll
        for (int s = 0; s < 16; ++s) v += s_part[s * 256 + tid];
        v = fmaxf(v, 0.f);
        s_h[tid] = v;
        float v2 = __shfl_xor(v, 1);
        if (!(tid & 1)) s_hb2[tid >> 1] = pack2(v, v2);
    }
    __syncthreads();

    // ---- wf: compute A (wf), prefetch P <- cw0; tail cols inline ----
    {
        LOADW8(P, cw0b, 512);
        vf4 a = {0.f, 0.f, 0.f, 0.f};
        DOT8(A, s_hb2);
        *(vf4*)(&s_part[sub * 260 + j4]) = a;
        if (jg < 4) {
            float e = 0.f;
            #pragma unroll
            for (int t = 0; t < 8; ++t) {
                uint w = *(const uint*)(wfb + (size_t)(sub + 16 * t) * 520 + 512 + jg * 2);
                e = dot2bf(w, s_hb2[sub + 16 * t], e);
            }
            s_part[sub * 260 + 256 + jg] = e;
        }
    }
    __syncthreads();
    if (tid < 259) {
        float v = s_bf[tid];
        #pragma unroll
        for (int s = 0; s < 16; ++s) v += s_part[s * 260 + tid];
        s_o[tid] = tanhf(v);
    }
    __syncthreads();

    // ---- state update + direct outputs ----
    if (tid < 256) {
        float nh = s_in[195 + tid] + s_o[3 + tid];
        orow[3 + tid] = nh;
        s_h[tid] = nh;
        float v2 = __shfl_xor(nh, 1);
        if (!(tid & 1)) s_hb2[tid >> 1] = pack2(nh, v2);
    }
    if (tid == 256) orow[0] = s_in[0] + s_o[0];
    if (tid == 257) orow[1] = s_in[1] + s_o[1];
    if (tid == 258) orow[2] = s_in[2] + s_o[2];
    __syncthreads();

    // ---- cw0: compute P (cw0), prefetch A <- crw ----
    {
        LOADW8(A, crwb, 512);
        vf4 a = {0.f, 0.f, 0.f, 0.f};
        DOT8(P, s_hb2);
        *(vf4*)(&s_part[sub * 256 + j4]) = a;
    }
    __syncthreads();
    if (tid < 256) {
        float v = s_cb0[tid];
        #pragma unroll
        for (int s = 0; s < 16; ++s) v += s_part[s * 256 + tid];
        v = fmaxf(v, 0.f);
        s_c[tid] = v;
        float v2 = __shfl_xor(v, 1);
        if (!(tid & 1)) s_cb2[tid >> 1] = pack2(v, v2);
    }
    __syncthreads();

    // ---- crw: compute A (crw) ----
    {
        vf4 a = {0.f, 0.f, 0.f, 0.f};
        DOT8(A, s_cb2);
        *(vf4*)(&s_part[sub * 256 + j4]) = a;
    }
    __syncthreads();
    if (tid < 256) {
        float v = s_crb[tid] + s_c[tid];
        #pragma unroll
        for (int s = 0; s < 16; ++s) v += s_part[s * 256 + tid];
        v = fmaxf(v, 0.f);
        float v2 = __shfl_xor(v, 1);
        if (!(tid & 1)) s_cb2[tid >> 1] = pack2(v, v2);
    }
    __syncthreads();

    // ---- logits pass 1: cols 0..511 (8-way kp split) ----
    int jg8 = tid & 127, sub8 = tid >> 7;
    int c4 = jg8 * 4;
    {
        uint4 wv[16]; uint hv[16];
        #pragma unroll
        for (int t = 0; t < 16; ++t)
            wv[t] = *(const uint4*)(cw1b + (size_t)(sub8 + 8 * t) * 2000 + c4 * 2);
        #pragma unroll
        for (int t = 0; t < 16; ++t) hv[t] = s_cb2[sub8 + 8 * t];
        vf4 a = {0.f, 0.f, 0.f, 0.f};
        #pragma unroll
        for (int t = 0; t < 16; ++t) {
            a[0] = dot2bf(wv[t].x, hv[t], a[0]);
            a[1] = dot2bf(wv[t].y, hv[t], a[1]);
            a[2] = dot2bf(wv[t].z, hv[t], a[2]);
            a[3] = dot2bf(wv[t].w, hv[t], a[3]);
        }
        *(vf4*)(&s_part[sub8 * 512 + c4]) = a;
    }
    __syncthreads();
    if (tid < 512) {
        float v = s_cb1[tid];
        #pragma unroll
        for (int s = 0; s < 8; ++s) v += s_part[s * 512 + tid];
        s_lg[tid] = v;
    }
    __syncthreads();

    // ---- logits pass 2: cols 512..999 ----
    {
        vf4 a = {0.f, 0.f, 0.f, 0.f};
        if (jg8 < 122) {
            uint4 wv[16]; uint hv[16];
            #pragma unroll
            for (int t = 0; t < 16; ++t)
                wv[t] = *(const uint4*)(cw1b + (size_t)(sub8 + 8 * t) * 2000 + (512 + c4) * 2);
            #pragma unroll
            for (int t = 0; t < 16; ++t) hv[t] = s_cb2[sub8 + 8 * t];
            #pragma unroll
            for (int t = 0; t < 16; ++t) {
                a[0] = dot2bf(wv[t].x, hv[t], a[0]);
                a[1] = dot2bf(wv[t].y, hv[t], a[1]);
                a[2] = dot2bf(wv[t].z, hv[t], a[2]);
                a[3] = dot2bf(wv[t].w, hv[t], a[3]);
            }
        }
        *(vf4*)(&s_part[sub8 * 512 + c4]) = a;
    }
    __syncthreads();
    if (tid < 488) {
        float v = s_cb1[512 + tid];
        #pragma unroll
        for (int s = 0; s < 8; ++s) v += s_part[s * 512 + tid];
        s_lg[512 + tid] = v;
    }
    __syncthreads();

    // ---- softmax over 1000 ----
    float lgv = (tid < 1000) ? s_lg[tid] : -1e30f;
    int lane = tid & 63, wid = tid >> 6;
    float m = lgv;
    #pragma unroll
    for (int off = 1; off < 64; off <<= 1) m = fmaxf(m, __shfl_xor(m, off));
    if (lane == 0) s_red[wid] = m;
    __syncthreads();
    m = s_red[0];
    #pragma unroll
    for (int w = 1; w < 16; ++w) m = fmaxf(m, s_red[w]);

    float e = (tid < 1000) ? expf(lgv - m) : 0.f;
    float lsum = e;
    #pragma unroll
    for (int off = 1; off < 64; off <<= 1) lsum += __shfl_xor(lsum, off);
    if (lane == 0) s_red[16 + wid] = lsum;
    __syncthreads();
    float total = 0.f;
    #pragma unroll
    for (int w = 0; w < 16; ++w) total += s_red[16 + w];

    if (tid < 1000) orow[259 + tid] = e / total;
}

extern "C" void kernel_launch(void* const* d_in, const int* in_sizes, int n_in,
                              void* d_out, int out_size, void* d_ws, size_t ws_size,
                              hipStream_t stream) {
    const float* image  = (const float*)d_in[0];
    const float* loc    = (const float*)d_in[1];
    const float* scl    = (const float*)d_in[2];
    const float* hidden = (const float*)d_in[3];
    const float* w0  = (const float*)d_in[4];
    const float* b0  = (const float*)d_in[5];
    const float* rw  = (const float*)d_in[6];
    const float* rb  = (const float*)d_in[7];
    const float* wf  = (const float*)d_in[8];
    const float* bf  = (const float*)d_in[9];
    const float* cw0 = (const float*)d_in[10];
    const float* cb0 = (const float*)d_in[11];
    const float* crw = (const float*)d_in[12];
    const float* crb = (const float*)d_in[13];
    const float* cw1 = (const float*)d_in[14];
    const float* cb1 = (const float*)d_in[15];

    float* ws   = (float*)d_ws;
    float* pix  = ws;                          // 24576 floats
    ushort* bfa = (ushort*)(ws + 24576);       // 838656 ushorts (~1.68 MB)
    float* sink = ws + 24576 + 419328 + 8;

    hipLaunchKernelGGL(interp_convert_kernel, dim3(384 + 512), dim3(256), 0, stream,
                       image, loc, scl, pix, w0, rw, wf, cw0, crw, cw1, bfa);
    hipLaunchKernelGGL(mlp_fused, dim3(256), dim3(1024), 0, stream,
                       loc, scl, hidden, pix, bfa,
                       b0, rb, bf, cb0, crb, cb1, (float*)d_out, sink);
}